// Round 4
// baseline (382.386 us; speedup 1.0000x reference)
//
#include <hip/hip_runtime.h>
#include <math.h>

#define BATCH  2
#define S_LEN  2048
#define DMODEL 1024
#define NH     16
#define DHEAD  64

typedef __attribute__((ext_vector_type(8))) short bf16x8;   // 8 bf16 = 4 VGPRs
typedef __attribute__((ext_vector_type(4))) float f32x4;

#define MFMA16(a,b,c) __builtin_amdgcn_mfma_f32_16x16x32_bf16((a),(b),(c),0,0,0)

__device__ __forceinline__ unsigned short f2bf(float x) {
    union { float f; unsigned int u; } v; v.f = x;
    unsigned int r = v.u + 0x7fffu + ((v.u >> 16) & 1u);   // RNE
    return (unsigned short)(r >> 16);
}
__device__ __forceinline__ float bf2f(unsigned short x) {
    union { float f; unsigned int u; } v; v.u = ((unsigned int)x) << 16;
    return v.f;
}
__device__ __forceinline__ unsigned int pk2(float a, float b) {
    return (unsigned int)f2bf(a) | ((unsigned int)f2bf(b) << 16);
}
__device__ __forceinline__ void gl2lds16(const void* g, void* l) {
    __builtin_amdgcn_global_load_lds(
        (const __attribute__((address_space(1))) void*)(g),
        (__attribute__((address_space(3))) void*)(l), 16, 0, 0);
}

// ---------------------------------------------------------------------------
// fp32 -> bf16 bulk convert, 8 elems/thread
// ---------------------------------------------------------------------------
__global__ __launch_bounds__(256) void cvt_bf16(
    const float* __restrict__ src, unsigned short* __restrict__ dst, int n8)
{
    int i = blockIdx.x * blockDim.x + threadIdx.x;
    if (i >= n8) return;
    float4 a = ((const float4*)src)[2*i];
    float4 b = ((const float4*)src)[2*i + 1];
    uint4 o;
    o.x = pk2(a.x, a.y); o.y = pk2(a.z, a.w);
    o.z = pk2(b.x, b.y); o.w = pk2(b.z, b.w);
    ((uint4*)dst)[i] = o;
}

// ---------------------------------------------------------------------------
// Projection GEMM: C[m=(b,s)][n] = sum_d Qbf[m][d] * W[n][d] + bias[n]
// 128x128 tile, BK=32, 4 waves (2x2 of 64x64). Epilogue goes through an LDS
// tile (union'd over the staging buffers) so global writes are 128B-contig
// dwordx4 runs instead of 8B scatter.
// z = 0/1 -> qw/kw [b,h,s,dk]; z = 2 -> vt [b,h,dv,s]
// ---------------------------------------------------------------------------
__global__ __launch_bounds__(256) void proj_mfma(
    const unsigned short* __restrict__ Abf,   // [4096][1024]
    const unsigned short* __restrict__ Wbf,   // [3][1024][1024]
    const float* __restrict__ bQ, const float* __restrict__ bK,
    const float* __restrict__ bV,
    unsigned short* __restrict__ qw, unsigned short* __restrict__ kw,
    unsigned short* __restrict__ vt)
{
    __shared__ union {
        struct { unsigned short At[128*32]; unsigned short Bt[128*32]; } s;
        unsigned short Ct[128*132];     // epilogue transpose tile (33.8 KB)
    } sm;

    const int tid  = threadIdx.x;
    const int lane = tid & 63;
    const int wv   = tid >> 6;
    const int wm   = (wv >> 1) * 64;
    const int wn   = (wv & 1) * 64;
    const int q15  = lane & 15;
    const int quad = lane >> 4;
    const int z    = blockIdx.z;
    const int n0   = blockIdx.x * 128;
    const int m0   = blockIdx.y * 128;

    const unsigned short* Wz = Wbf + (size_t)z * DMODEL * DMODEL;
    const float* bias = (z == 0) ? bQ : ((z == 1) ? bK : bV);

    f32x4 zero4 = {0.f, 0.f, 0.f, 0.f};
    f32x4 acc[4][4];
    #pragma unroll
    for (int i = 0; i < 4; ++i)
        #pragma unroll
        for (int j = 0; j < 4; ++j) acc[i][j] = zero4;

    for (int k0 = 0; k0 < DMODEL; k0 += 32) {
        __syncthreads();   // previous readers done
        #pragma unroll
        for (int c = 0; c < 2; ++c) {
            int o   = tid * 16 + c * 4096;      // byte offset in 8KB tile
            int row = o >> 6;                   // 64B per row (32 bf16)
            int cb  = o & 63;
            gl2lds16(Abf + (size_t)(m0 + row) * DMODEL + k0 + (cb >> 1),
                     (char*)sm.s.At + o);
            gl2lds16(Wz  + (size_t)(n0 + row) * DMODEL + k0 + (cb >> 1),
                     (char*)sm.s.Bt + o);
        }
        __syncthreads();   // vmcnt(0) drained by barrier

        bf16x8 af[4], bf[4];
        #pragma unroll
        for (int i = 0; i < 4; ++i)
            af[i] = *(const bf16x8*)(sm.s.At + (wm + i*16 + q15) * 32 + quad * 8);
        #pragma unroll
        for (int j = 0; j < 4; ++j)
            bf[j] = *(const bf16x8*)(sm.s.Bt + (wn + j*16 + q15) * 32 + quad * 8);

        if (z < 2) {
            // D[m = n-local quad*4+r][n = m-local q15]: pack along n
            #pragma unroll
            for (int i = 0; i < 4; ++i)
                #pragma unroll
                for (int j = 0; j < 4; ++j)
                    acc[i][j] = MFMA16(bf[j], af[i], acc[i][j]);
        } else {
            // D[m = m-local quad*4+r][n = n-local q15]: pack along m (s)
            #pragma unroll
            for (int i = 0; i < 4; ++i)
                #pragma unroll
                for (int j = 0; j < 4; ++j)
                    acc[i][j] = MFMA16(af[i], bf[j], acc[i][j]);
        }
    }

    __syncthreads();   // done with At/Bt; Ct aliases them

    if (z < 2) {
        // Ct[m_local][n_local], 4 n-contig bf16 per lane-frag
        #pragma unroll
        for (int i = 0; i < 4; ++i) {
            int ml = wm + i*16 + q15;
            #pragma unroll
            for (int j = 0; j < 4; ++j) {
                int nl = wn + j*16 + quad*4;
                float4 b4 = *(const float4*)(bias + n0 + nl);
                f32x4 v = acc[i][j];
                uint2 u;
                u.x = pk2(v.x + b4.x, v.y + b4.y);
                u.y = pk2(v.z + b4.z, v.w + b4.w);
                *(uint2*)&sm.Ct[ml*132 + nl] = u;
            }
        }
    } else {
        // Ct[n_local][m_local], 4 m(s)-contig bf16 per lane-frag
        #pragma unroll
        for (int j = 0; j < 4; ++j) {
            int nl = wn + j*16 + q15;
            float bv = bias[n0 + nl];
            #pragma unroll
            for (int i = 0; i < 4; ++i) {
                int ml = wm + i*16 + quad*4;
                f32x4 v = acc[i][j];
                uint2 u;
                u.x = pk2(v.x + bv, v.y + bv);
                u.y = pk2(v.z + bv, v.w + bv);
                *(uint2*)&sm.Ct[nl*132 + ml] = u;
            }
        }
    }
    __syncthreads();

    // cooperative write-out: thread t -> Ct row t>>1, 64-short half (t&1)
    {
        int row  = tid >> 1;
        int half = (tid & 1) * 64;
        const uint4* src = (const uint4*)&sm.Ct[row*132 + half];
        unsigned short* dst;
        if (z < 2) {
            unsigned short* outp = (z == 0) ? qw : kw;
            int mg = m0 + row;  int b2 = mg >> 11, s = mg & 2047;
            int n  = n0 + half; int hh = n >> 6;           // dk = 0
            dst = outp + (((size_t)b2*NH + hh)*S_LEN + s)*DHEAD;
        } else {
            int n  = n0 + row;  int hh = n >> 6, dv = n & 63;
            int b2 = m0 >> 11, s0 = m0 & 2047;
            dst = vt + (((size_t)b2*NH + hh)*DHEAD + dv)*S_LEN + s0 + half;
        }
        #pragma unroll
        for (int c = 0; c < 8; ++c) ((uint4*)dst)[c] = src[c];
    }
}

// ---------------------------------------------------------------------------
// Attention: block = (64-q tile, h, b), 4 waves x 16 q-rows. NO barriers:
// P is per-wave-private LDS (same-wave LDS ordering is compiler-enforced).
// QK^T computed with K as the A operand so each lane holds 4 consecutive
// keys for one query -> packed b64 P writes, float4 mask loads.
// ---------------------------------------------------------------------------
__global__ __launch_bounds__(256) void attn_mfma(
    const unsigned short* __restrict__ qw, const unsigned short* __restrict__ kw,
    const unsigned short* __restrict__ vt, const float* __restrict__ mask,
    float* __restrict__ out)
{
    __shared__ __align__(16) unsigned short P[4][16][72];  // per-wave, 144B rows

    const int tid  = threadIdx.x;
    const int lane = tid & 63;
    const int wv   = tid >> 6;
    const int q15  = lane & 15;
    const int quad = lane >> 4;
    const int q0   = blockIdx.x * 64;
    const int h    = blockIdx.y;
    const int b    = blockIdx.z;

    const size_t headoff = ((size_t)b * NH + h) * S_LEN * DHEAD;
    const unsigned short* qb = qw + headoff;
    const unsigned short* kb = kw + headoff;
    const unsigned short* vb = vt + headoff;        // [dv][s]
    const float* mkp = mask + (size_t)b * S_LEN;

    // Q as B operand: B[k=d at quad*8+j][n=query at lane&15]
    const unsigned short* qrow = qb + (size_t)(q0 + wv*16 + q15)*DHEAD;
    bf16x8 qf0 = *(const bf16x8*)(qrow + quad*8);
    bf16x8 qf1 = *(const bf16x8*)(qrow + 32 + quad*8);

    f32x4 zero4 = {0.f, 0.f, 0.f, 0.f};
    f32x4 oacc[4];
    #pragma unroll
    for (int j = 0; j < 4; ++j) oacc[j] = zero4;
    float rsq = 0.f;                 // partial denom for query q15
    const float scale = 0.125f;      // 1/sqrt(64)

    for (int k0 = 0; k0 < S_LEN; k0 += 64) {
        // ---- QK^T: D[m=key quad*4+r][n=query q15] ----
        #pragma unroll
        for (int ks = 0; ks < 4; ++ks) {
            const unsigned short* kr = kb + (size_t)(k0 + ks*16 + q15)*DHEAD;
            bf16x8 kf0 = *(const bf16x8*)(kr + quad*8);
            bf16x8 kf1 = *(const bf16x8*)(kr + 32 + quad*8);
            f32x4 s4 = zero4;
            s4 = MFMA16(kf0, qf0, s4);
            s4 = MFMA16(kf1, qf1, s4);
            float4 m4 = *(const float4*)(mkp + k0 + ks*16 + quad*4);
            float mm[4] = {m4.x, m4.y, m4.z, m4.w};
            unsigned long long pack = 0;
            #pragma unroll
            for (int r = 0; r < 4; ++r) {
                unsigned short pb = f2bf(__expf(s4[r] * scale) * mm[r]);
                rsq += bf2f(pb);     // denominator matches bf16 numerator
                pack |= (unsigned long long)pb << (16*r);
            }
            *(unsigned long long*)&P[wv][q15][ks*16 + quad*4] = pack;
        }
        // ---- PV: A = P[query][key] (b128 reads), B = V^T rows from global ----
        bf16x8 pf0 = *(const bf16x8*)(&P[wv][q15][quad*8]);
        bf16x8 pf1 = *(const bf16x8*)(&P[wv][q15][32 + quad*8]);
        #pragma unroll
        for (int nj = 0; nj < 4; ++nj) {
            const unsigned short* vr = vb + (size_t)(nj*16 + q15)*S_LEN + k0;
            bf16x8 vf0 = *(const bf16x8*)(vr + quad*8);
            bf16x8 vf1 = *(const bf16x8*)(vr + 32 + quad*8);
            oacc[nj] = MFMA16(pf0, vf0, oacc[nj]);
            oacc[nj] = MFMA16(pf1, vf1, oacc[nj]);
        }
    }

    // full denom for query q15 lives across the 4 quad-groups
    float v = rsq;
    v += __shfl_xor(v, 16);
    v += __shfl_xor(v, 32);
    float invq = 1.0f / (v + 1e-8f);

    // out[b][s][h*64+dv]; s = q0+wv*16+quad*4+r, dv = nj*16+q15
    #pragma unroll
    for (int r = 0; r < 4; ++r) {
        float inv = __shfl(invq, quad*4 + r);   // lane holding query quad*4+r
        size_t row = ((size_t)b*S_LEN + q0 + wv*16 + quad*4 + r)*DMODEL + h*DHEAD;
        #pragma unroll
        for (int nj = 0; nj < 4; ++nj)
            out[row + nj*16 + q15] = oacc[nj][r] * inv;
    }
}

// ---------------------------------------------------------------------------
extern "C" void kernel_launch(void* const* d_in, const int* in_sizes, int n_in,
                              void* d_out, int out_size, void* d_ws, size_t ws_size,
                              hipStream_t stream) {
    const float* Q    = (const float*)d_in[0];
    const float* msk  = (const float*)d_in[1];
    const float* W_Q  = (const float*)d_in[2];
    const float* b_Q  = (const float*)d_in[3];
    const float* W_K  = (const float*)d_in[4];
    const float* b_K  = (const float*)d_in[5];
    const float* W_V  = (const float*)d_in[6];
    const float* b_V  = (const float*)d_in[7];
    float* out = (float*)d_out;

    unsigned short* wsu = (unsigned short*)d_ws;
    unsigned short* Qbf = wsu;                                   // 4M elems
    unsigned short* Wbf = Qbf + (size_t)4096*1024;               // 3M
    unsigned short* qwb = Wbf + (size_t)3*1024*1024;             // 4M
    unsigned short* kwb = qwb + (size_t)4*1024*1024;             // 4M
    unsigned short* vtb = kwb + (size_t)4*1024*1024;             // 4M (38MB)

    cvt_bf16<<<2048, 256, 0, stream>>>(Q,   Qbf,                4096*1024/8);
    cvt_bf16<<<512,  256, 0, stream>>>(W_Q, Wbf,                1024*1024/8);
    cvt_bf16<<<512,  256, 0, stream>>>(W_K, Wbf + 1024*1024,    1024*1024/8);
    cvt_bf16<<<512,  256, 0, stream>>>(W_V, Wbf + 2*1024*1024,  1024*1024/8);

    proj_mfma<<<dim3(8, 32, 3), 256, 0, stream>>>(
        Qbf, Wbf, b_Q, b_K, b_V, qwb, kwb, vtb);

    attn_mfma<<<dim3(S_LEN/64, NH, BATCH), 256, 0, stream>>>(
        qwb, kwb, vtb, msk, out);
}

// Round 5
// 195.203 us; speedup vs baseline: 1.9589x; 1.9589x over previous
//
#include <hip/hip_runtime.h>
#include <hip/hip_bf16.h>
#include <math.h>

#define BATCH  2
#define S_LEN  2048
#define DMODEL 1024
#define NH     16
#define DHEAD  64

typedef __attribute__((ext_vector_type(8))) short bf16x8;   // 8 bf16 = 4 VGPRs
typedef __attribute__((ext_vector_type(4))) float f32x4;

#define MFMA16(a,b,c) __builtin_amdgcn_mfma_f32_16x16x32_bf16((a),(b),(c),0,0,0)

__device__ __forceinline__ unsigned int pkbf(float a, float b) {
    __hip_bfloat162 h = __float22bfloat162_rn(make_float2(a, b));
    union { __hip_bfloat162 h; unsigned int u; } v; v.h = h; return v.u;
}
__device__ __forceinline__ void gl2lds16(const void* g, void* l) {
    __builtin_amdgcn_global_load_lds(
        (const __attribute__((address_space(1))) void*)(g),
        (__attribute__((address_space(3))) void*)(l), 16, 0, 0);
}

// ---------------------------------------------------------------------------
// fp32 -> bf16 bulk convert, 8 elems/thread
// ---------------------------------------------------------------------------
__global__ __launch_bounds__(256) void cvt_bf16(
    const float* __restrict__ src, unsigned short* __restrict__ dst, int n8)
{
    int i = blockIdx.x * blockDim.x + threadIdx.x;
    if (i >= n8) return;
    float4 a = ((const float4*)src)[2*i];
    float4 b = ((const float4*)src)[2*i + 1];
    uint4 o;
    o.x = pkbf(a.x, a.y); o.y = pkbf(a.z, a.w);
    o.z = pkbf(b.x, b.y); o.w = pkbf(b.z, b.w);
    ((uint4*)dst)[i] = o;
}

// ---------------------------------------------------------------------------
// Projection GEMM with folds:
//   z=0 -> qw [b,h,s,dk], output scaled by 0.125 (1/sqrt(dk), exact pow2)
//   z=1 -> kw [b,h,s,dk]
//   z=2 -> vt [b,h,dv,s], output multiplied by mask[b][s] (V' = mask*V)
// 128x128 tile, BK=32, 4 waves; epilogue through LDS for contiguous stores.
// ---------------------------------------------------------------------------
__global__ __launch_bounds__(256) void proj_mfma(
    const unsigned short* __restrict__ Abf,   // [4096][1024]
    const unsigned short* __restrict__ Wbf,   // [3][1024][1024]
    const float* __restrict__ bQ, const float* __restrict__ bK,
    const float* __restrict__ bV, const float* __restrict__ mask,
    unsigned short* __restrict__ qw, unsigned short* __restrict__ kw,
    unsigned short* __restrict__ vt)
{
    __shared__ union {
        struct { unsigned short At[128*32]; unsigned short Bt[128*32]; } s;
        unsigned short Ct[128*132];     // epilogue transpose tile (33.8 KB)
    } sm;

    const int tid  = threadIdx.x;
    const int lane = tid & 63;
    const int wv   = tid >> 6;
    const int wm   = (wv >> 1) * 64;
    const int wn   = (wv & 1) * 64;
    const int q15  = lane & 15;
    const int quad = lane >> 4;
    const int z    = blockIdx.z;
    const int n0   = blockIdx.x * 128;
    const int m0   = blockIdx.y * 128;

    const unsigned short* Wz = Wbf + (size_t)z * DMODEL * DMODEL;
    const float* bias = (z == 0) ? bQ : ((z == 1) ? bK : bV);

    f32x4 zero4 = {0.f, 0.f, 0.f, 0.f};
    f32x4 acc[4][4];
    #pragma unroll
    for (int i = 0; i < 4; ++i)
        #pragma unroll
        for (int j = 0; j < 4; ++j) acc[i][j] = zero4;

    for (int k0 = 0; k0 < DMODEL; k0 += 32) {
        __syncthreads();
        #pragma unroll
        for (int c = 0; c < 2; ++c) {
            int o   = tid * 16 + c * 4096;
            int row = o >> 6;
            int cb  = o & 63;
            gl2lds16(Abf + (size_t)(m0 + row) * DMODEL + k0 + (cb >> 1),
                     (char*)sm.s.At + o);
            gl2lds16(Wz  + (size_t)(n0 + row) * DMODEL + k0 + (cb >> 1),
                     (char*)sm.s.Bt + o);
        }
        __syncthreads();

        bf16x8 af[4], bf[4];
        #pragma unroll
        for (int i = 0; i < 4; ++i)
            af[i] = *(const bf16x8*)(sm.s.At + (wm + i*16 + q15) * 32 + quad * 8);
        #pragma unroll
        for (int j = 0; j < 4; ++j)
            bf[j] = *(const bf16x8*)(sm.s.Bt + (wn + j*16 + q15) * 32 + quad * 8);

        if (z < 2) {
            #pragma unroll
            for (int i = 0; i < 4; ++i)
                #pragma unroll
                for (int j = 0; j < 4; ++j)
                    acc[i][j] = MFMA16(bf[j], af[i], acc[i][j]);
        } else {
            #pragma unroll
            for (int i = 0; i < 4; ++i)
                #pragma unroll
                for (int j = 0; j < 4; ++j)
                    acc[i][j] = MFMA16(af[i], bf[j], acc[i][j]);
        }
    }

    __syncthreads();   // done with At/Bt; Ct aliases them

    if (z < 2) {
        const float qs = (z == 0) ? 0.125f : 1.0f;   // fold 1/sqrt(dk) into Q
        #pragma unroll
        for (int i = 0; i < 4; ++i) {
            int ml = wm + i*16 + q15;
            #pragma unroll
            for (int j = 0; j < 4; ++j) {
                int nl = wn + j*16 + quad*4;
                float4 b4 = *(const float4*)(bias + n0 + nl);
                f32x4 v = acc[i][j];
                uint2 u;
                u.x = pkbf((v.x + b4.x)*qs, (v.y + b4.y)*qs);
                u.y = pkbf((v.z + b4.z)*qs, (v.w + b4.w)*qs);
                *(uint2*)&sm.Ct[ml*132 + nl] = u;
            }
        }
    } else {
        // V' = mask * (acc + bias); acc packed along m = s (4 consecutive)
        #pragma unroll
        for (int i = 0; i < 4; ++i) {
            int ml = wm + i*16 + quad*4;
            int sg = m0 + ml;
            int b2 = sg >> 11, s0g = sg & 2047;
            float4 mk4 = *(const float4*)(mask + (size_t)b2*S_LEN + s0g);
            #pragma unroll
            for (int j = 0; j < 4; ++j) {
                int nl = wn + j*16 + q15;
                float bv = bias[n0 + nl];
                f32x4 v = acc[i][j];
                uint2 u;
                u.x = pkbf((v.x + bv)*mk4.x, (v.y + bv)*mk4.y);
                u.y = pkbf((v.z + bv)*mk4.z, (v.w + bv)*mk4.w);
                *(uint2*)&sm.Ct[nl*132 + ml] = u;
            }
        }
    }
    __syncthreads();

    {
        int row  = tid >> 1;
        int half = (tid & 1) * 64;
        const uint4* src = (const uint4*)&sm.Ct[row*132 + half];
        unsigned short* dst;
        if (z < 2) {
            unsigned short* outp = (z == 0) ? qw : kw;
            int mg = m0 + row;  int b2 = mg >> 11, s = mg & 2047;
            int n  = n0 + half; int hh = n >> 6;
            dst = outp + (((size_t)b2*NH + hh)*S_LEN + s)*DHEAD;
        } else {
            int n  = n0 + row;  int hh = n >> 6, dv = n & 63;
            int b2 = m0 >> 11, s0 = m0 & 2047;
            dst = vt + (((size_t)b2*NH + hh)*DHEAD + dv)*S_LEN + s0 + half;
        }
        #pragma unroll
        for (int c = 0; c < 8; ++c) ((uint4*)dst)[c] = src[c];
    }
}

// ---------------------------------------------------------------------------
// Attention: block = 128 queries x (h, b); 4 waves x 32 queries.
// K/V/mask tiles double-buffered in LDS with register prefetch; single
// barrier per tile. Q pre-scaled by 0.125; V pre-multiplied by mask;
// denominator = P @ mask via MFMA (no scalar reductions at all).
// ---------------------------------------------------------------------------
__global__ __launch_bounds__(256, 2) void attn_mfma(
    const unsigned short* __restrict__ qw, const unsigned short* __restrict__ kw,
    const unsigned short* __restrict__ vt, const unsigned short* __restrict__ mbf,
    float* __restrict__ out)
{
    __shared__ __align__(16) unsigned short Ks[2][64][72];   // [key][d]
    __shared__ __align__(16) unsigned short Vs[2][64][72];   // [dv][key]
    __shared__ __align__(16) unsigned short Ms[2][72];       // mask bf16
    __shared__ __align__(16) unsigned short P [4][32][72];   // per-wave

    const int tid  = threadIdx.x;
    const int lane = tid & 63;
    const int wv   = tid >> 6;
    const int q15  = lane & 15;
    const int quad = lane >> 4;
    const int q0   = blockIdx.x * 128;
    const int h    = blockIdx.y;
    const int b    = blockIdx.z;

    const size_t headoff = ((size_t)b * NH + h) * S_LEN * DHEAD;
    const unsigned short* qb = qw + headoff;
    const unsigned short* kb = kw + headoff;
    const unsigned short* vb = vt + headoff;          // [dv][s]
    const unsigned short* mb = mbf + (size_t)b * S_LEN;

    // Q fragments (B-operand): B[k=d at quad*8+j][n=query at lane&15]
    bf16x8 qf[2][2];
    #pragma unroll
    for (int qi = 0; qi < 2; ++qi) {
        const unsigned short* qr = qb + (size_t)(q0 + wv*32 + qi*16 + q15)*DHEAD;
        qf[qi][0] = *(const bf16x8*)(qr + quad*8);
        qf[qi][1] = *(const bf16x8*)(qr + 32 + quad*8);
    }

    const int srow = tid >> 3;          // 0..31
    const int scol = (tid & 7) * 8;     // 0..56

    f32x4 zero4 = {0.f, 0.f, 0.f, 0.f};
    f32x4 oacc[2][4];
    f32x4 dacc[2];
    #pragma unroll
    for (int qi = 0; qi < 2; ++qi) {
        dacc[qi] = zero4;
        #pragma unroll
        for (int nj = 0; nj < 4; ++nj) oacc[qi][nj] = zero4;
    }

    // prologue: prefetch tile 0 into registers
    uint4 kr0, kr1, vr0, vr1, mr = {0,0,0,0};
    kr0 = *(const uint4*)(kb + (size_t)(srow)     *DHEAD + scol);
    kr1 = *(const uint4*)(kb + (size_t)(srow + 32)*DHEAD + scol);
    vr0 = *(const uint4*)(vb + (size_t)(srow)     *S_LEN + scol);
    vr1 = *(const uint4*)(vb + (size_t)(srow + 32)*S_LEN + scol);
    if (tid < 8) mr = *(const uint4*)(mb + tid*8);

    for (int t = 0; t < 32; ++t) {
        const int buf = t & 1;
        const int k0  = t * 64;
        // commit staged regs to LDS[buf]
        *(uint4*)&Ks[buf][srow][scol]      = kr0;
        *(uint4*)&Ks[buf][srow + 32][scol] = kr1;
        *(uint4*)&Vs[buf][srow][scol]      = vr0;
        *(uint4*)&Vs[buf][srow + 32][scol] = vr1;
        if (tid < 8) *(uint4*)&Ms[buf][tid*8] = mr;
        // issue prefetch for tile t+1 (clamped; overlaps compute below)
        const int kn = (t < 31) ? k0 + 64 : 0;
        kr0 = *(const uint4*)(kb + (size_t)(kn + srow)     *DHEAD + scol);
        kr1 = *(const uint4*)(kb + (size_t)(kn + srow + 32)*DHEAD + scol);
        vr0 = *(const uint4*)(vb + (size_t)(srow)     *S_LEN + kn + scol);
        vr1 = *(const uint4*)(vb + (size_t)(srow + 32)*S_LEN + kn + scol);
        if (tid < 8) mr = *(const uint4*)(mb + kn + tid*8);
        __syncthreads();

        // ---- QK^T: D[m=key quad*4+r][n=query q15] ----
        f32x4 s[2][4];
        #pragma unroll
        for (int ks = 0; ks < 4; ++ks) {
            bf16x8 kf0 = *(const bf16x8*)&Ks[buf][ks*16 + q15][quad*8];
            bf16x8 kf1 = *(const bf16x8*)&Ks[buf][ks*16 + q15][32 + quad*8];
            #pragma unroll
            for (int qi = 0; qi < 2; ++qi) {
                f32x4 a = MFMA16(kf0, qf[qi][0], zero4);
                s[qi][ks] = MFMA16(kf1, qf[qi][1], a);
            }
        }
        // ---- exp + pack -> P (b64 writes, wave-private) ----
        #pragma unroll
        for (int qi = 0; qi < 2; ++qi)
            #pragma unroll
            for (int ks = 0; ks < 4; ++ks) {
                float e0 = __expf(s[qi][ks][0]);
                float e1 = __expf(s[qi][ks][1]);
                float e2 = __expf(s[qi][ks][2]);
                float e3 = __expf(s[qi][ks][3]);
                uint2 u; u.x = pkbf(e0, e1); u.y = pkbf(e2, e3);
                *(uint2*)&P[wv][qi*16 + q15][ks*16 + quad*4] = u;
            }
        // ---- P fragments (A-operand) ----
        bf16x8 pf[2][2];
        #pragma unroll
        for (int qi = 0; qi < 2; ++qi) {
            pf[qi][0] = *(const bf16x8*)&P[wv][qi*16 + q15][quad*8];
            pf[qi][1] = *(const bf16x8*)&P[wv][qi*16 + q15][32 + quad*8];
        }
        // ---- denominator: P @ mask ----
        bf16x8 mf0 = *(const bf16x8*)&Ms[buf][quad*8];
        bf16x8 mf1 = *(const bf16x8*)&Ms[buf][32 + quad*8];
        #pragma unroll
        for (int qi = 0; qi < 2; ++qi) {
            dacc[qi] = MFMA16(pf[qi][0], mf0, dacc[qi]);
            dacc[qi] = MFMA16(pf[qi][1], mf1, dacc[qi]);
        }
        // ---- PV: V' rows (already mask-scaled) from LDS ----
        #pragma unroll
        for (int nj = 0; nj < 4; ++nj) {
            bf16x8 vf0 = *(const bf16x8*)&Vs[buf][nj*16 + q15][quad*8];
            bf16x8 vf1 = *(const bf16x8*)&Vs[buf][nj*16 + q15][32 + quad*8];
            #pragma unroll
            for (int qi = 0; qi < 2; ++qi) {
                oacc[qi][nj] = MFMA16(pf[qi][0], vf0, oacc[qi][nj]);
                oacc[qi][nj] = MFMA16(pf[qi][1], vf1, oacc[qi][nj]);
            }
        }
    }

    // epilogue: D rows quad*4+r = query; denom replicated across n lanes
    #pragma unroll
    for (int qi = 0; qi < 2; ++qi)
        #pragma unroll
        for (int r = 0; r < 4; ++r) {
            float inv = 1.0f / (dacc[qi][r] + 1e-8f);
            size_t row = ((size_t)b*S_LEN + q0 + wv*32 + qi*16 + quad*4 + r)*DMODEL
                       + h*DHEAD;
            #pragma unroll
            for (int nj = 0; nj < 4; ++nj)
                out[row + nj*16 + q15] = oacc[qi][nj][r] * inv;
        }
}

// ---------------------------------------------------------------------------
extern "C" void kernel_launch(void* const* d_in, const int* in_sizes, int n_in,
                              void* d_out, int out_size, void* d_ws, size_t ws_size,
                              hipStream_t stream) {
    const float* Q    = (const float*)d_in[0];
    const float* msk  = (const float*)d_in[1];
    const float* W_Q  = (const float*)d_in[2];
    const float* b_Q  = (const float*)d_in[3];
    const float* W_K  = (const float*)d_in[4];
    const float* b_K  = (const float*)d_in[5];
    const float* W_V  = (const float*)d_in[6];
    const float* b_V  = (const float*)d_in[7];
    float* out = (float*)d_out;

    unsigned short* wsu = (unsigned short*)d_ws;
    unsigned short* Qbf = wsu;                                   // 4M elems
    unsigned short* Wbf = Qbf + (size_t)4096*1024;               // 3M
    unsigned short* qwb = Wbf + (size_t)3*1024*1024;             // 4M
    unsigned short* kwb = qwb + (size_t)4*1024*1024;             // 4M
    unsigned short* vtb = kwb + (size_t)4*1024*1024;             // 4M
    unsigned short* mbf = vtb + (size_t)4*1024*1024;             // 4K (38MB+8KB)

    cvt_bf16<<<2048, 256, 0, stream>>>(Q,   Qbf,                4096*1024/8);
    cvt_bf16<<<512,  256, 0, stream>>>(W_Q, Wbf,                1024*1024/8);
    cvt_bf16<<<512,  256, 0, stream>>>(W_K, Wbf + 1024*1024,    1024*1024/8);
    cvt_bf16<<<512,  256, 0, stream>>>(W_V, Wbf + 2*1024*1024,  1024*1024/8);
    cvt_bf16<<<2,    256, 0, stream>>>(msk, mbf,                BATCH*S_LEN/8);

    proj_mfma<<<dim3(8, 32, 3), 256, 0, stream>>>(
        Qbf, Wbf, b_Q, b_K, b_V, msk, qwb, kwb, vtb);

    attn_mfma<<<dim3(S_LEN/128, NH, BATCH), 256, 0, stream>>>(
        qwb, kwb, vtb, mbf, out);
}

// Round 7
// 181.061 us; speedup vs baseline: 2.1119x; 1.0781x over previous
//
#include <hip/hip_runtime.h>
#include <hip/hip_bf16.h>
#include <math.h>

#define BATCH  2
#define S_LEN  2048
#define DMODEL 1024
#define NH     16
#define DHEAD  64

typedef __attribute__((ext_vector_type(8))) short bf16x8;   // 8 bf16 = 4 VGPRs
typedef __attribute__((ext_vector_type(4))) float f32x4;

#define MFMA16(a,b,c) __builtin_amdgcn_mfma_f32_16x16x32_bf16((a),(b),(c),0,0,0)

// Q pre-scale: (1/sqrt(64)) * log2(e) so attention uses exp2 directly
#define QSCALE 0.18033688011110793f
#define EXP2F(x) __builtin_amdgcn_exp2f(x)

__device__ __forceinline__ unsigned int pkbf(float a, float b) {
    __hip_bfloat162 h = __float22bfloat162_rn(make_float2(a, b));
    union { __hip_bfloat162 h; unsigned int u; } v; v.h = h; return v.u;
}
__device__ __forceinline__ void gl2lds16(const void* g, void* l) {
    __builtin_amdgcn_global_load_lds(
        (const __attribute__((address_space(1))) void*)(g),
        (__attribute__((address_space(3))) void*)(l), 16, 0, 0);
}

// ---------------------------------------------------------------------------
// Single fused fp32->bf16 convert for Q, W_Q|W_K|W_V, mask. 8 elems/unit.
// Layout: units [0,524288) = Q; [524288,917504) = W (3x131072); tail = mask.
// ---------------------------------------------------------------------------
__global__ __launch_bounds__(256) void cvt_all(
    const float* __restrict__ Q,  const float* __restrict__ WQ,
    const float* __restrict__ WK, const float* __restrict__ WV,
    const float* __restrict__ msk,
    unsigned short* __restrict__ Qbf, unsigned short* __restrict__ Wbf,
    unsigned short* __restrict__ mbf)
{
    int i = blockIdx.x * blockDim.x + threadIdx.x;   // grid covers 918016 units
    const float* src;
    unsigned short* dst;
    int off;
    if (i < 524288) {
        src = Q; dst = Qbf; off = i;
    } else if (i < 917504) {
        int j = i - 524288;                  // [0, 393216)
        int which = j >> 17;                 // /131072
        src = (which == 0) ? WQ : ((which == 1) ? WK : WV);
        dst = Wbf + ((size_t)which << 20);   // which * 1048576
        off = j & 131071;
    } else {
        int j = i - 917504;
        if (j >= 512) return;
        src = msk; dst = mbf; off = j;
    }
    float4 a = ((const float4*)src)[2*off];
    float4 b = ((const float4*)src)[2*off + 1];
    uint4 o;
    o.x = pkbf(a.x, a.y); o.y = pkbf(a.z, a.w);
    o.z = pkbf(b.x, b.y); o.w = pkbf(b.z, b.w);
    ((uint4*)dst)[off] = o;
}

// ---------------------------------------------------------------------------
// Projection GEMM with folds:
//   z=0 -> qw [b,h,s,dk], output scaled by QSCALE (1/sqrt(dk) * log2e)
//   z=1 -> kw [b,h,s,dk]
//   z=2 -> vt [b,h,dv,s], output multiplied by mask[b][s] (V' = mask*V)
// 128x128 tile, BK=32, 4 waves; epilogue through LDS for contiguous stores.
// ---------------------------------------------------------------------------
__global__ __launch_bounds__(256) void proj_mfma(
    const unsigned short* __restrict__ Abf,   // [4096][1024]
    const unsigned short* __restrict__ Wbf,   // [3][1024][1024]
    const float* __restrict__ bQ, const float* __restrict__ bK,
    const float* __restrict__ bV, const float* __restrict__ mask,
    unsigned short* __restrict__ qw, unsigned short* __restrict__ kw,
    unsigned short* __restrict__ vt)
{
    __shared__ union {
        struct { unsigned short At[128*32]; unsigned short Bt[128*32]; } s;
        unsigned short Ct[128*132];     // epilogue transpose tile (33.8 KB)
    } sm;

    const int tid  = threadIdx.x;
    const int lane = tid & 63;
    const int wv   = tid >> 6;
    const int wm   = (wv >> 1) * 64;
    const int wn   = (wv & 1) * 64;
    const int q15  = lane & 15;
    const int quad = lane >> 4;
    const int z    = blockIdx.z;
    const int n0   = blockIdx.x * 128;
    const int m0   = blockIdx.y * 128;

    const unsigned short* Wz = Wbf + (size_t)z * DMODEL * DMODEL;
    const float* bias = (z == 0) ? bQ : ((z == 1) ? bK : bV);

    f32x4 zero4 = {0.f, 0.f, 0.f, 0.f};
    f32x4 acc[4][4];
    #pragma unroll
    for (int i = 0; i < 4; ++i)
        #pragma unroll
        for (int j = 0; j < 4; ++j) acc[i][j] = zero4;

    for (int k0 = 0; k0 < DMODEL; k0 += 32) {
        __syncthreads();
        #pragma unroll
        for (int c = 0; c < 2; ++c) {
            int o   = tid * 16 + c * 4096;
            int row = o >> 6;
            int cb  = o & 63;
            gl2lds16(Abf + (size_t)(m0 + row) * DMODEL + k0 + (cb >> 1),
                     (char*)sm.s.At + o);
            gl2lds16(Wz  + (size_t)(n0 + row) * DMODEL + k0 + (cb >> 1),
                     (char*)sm.s.Bt + o);
        }
        __syncthreads();

        bf16x8 af[4], bf[4];
        #pragma unroll
        for (int i = 0; i < 4; ++i)
            af[i] = *(const bf16x8*)(sm.s.At + (wm + i*16 + q15) * 32 + quad * 8);
        #pragma unroll
        for (int j = 0; j < 4; ++j)
            bf[j] = *(const bf16x8*)(sm.s.Bt + (wn + j*16 + q15) * 32 + quad * 8);

        if (z < 2) {
            #pragma unroll
            for (int i = 0; i < 4; ++i)
                #pragma unroll
                for (int j = 0; j < 4; ++j)
                    acc[i][j] = MFMA16(bf[j], af[i], acc[i][j]);
        } else {
            #pragma unroll
            for (int i = 0; i < 4; ++i)
                #pragma unroll
                for (int j = 0; j < 4; ++j)
                    acc[i][j] = MFMA16(af[i], bf[j], acc[i][j]);
        }
    }

    __syncthreads();   // done with At/Bt; Ct aliases them

    if (z < 2) {
        const float qs = (z == 0) ? QSCALE : 1.0f;
        #pragma unroll
        for (int i = 0; i < 4; ++i) {
            int ml = wm + i*16 + q15;
            #pragma unroll
            for (int j = 0; j < 4; ++j) {
                int nl = wn + j*16 + quad*4;
                float4 b4 = *(const float4*)(bias + n0 + nl);
                f32x4 v = acc[i][j];
                uint2 u;
                u.x = pkbf((v.x + b4.x)*qs, (v.y + b4.y)*qs);
                u.y = pkbf((v.z + b4.z)*qs, (v.w + b4.w)*qs);
                *(uint2*)&sm.Ct[ml*132 + nl] = u;
            }
        }
    } else {
        #pragma unroll
        for (int i = 0; i < 4; ++i) {
            int ml = wm + i*16 + quad*4;
            int sg = m0 + ml;
            int b2 = sg >> 11, s0g = sg & 2047;
            float4 mk4 = *(const float4*)(mask + (size_t)b2*S_LEN + s0g);
            #pragma unroll
            for (int j = 0; j < 4; ++j) {
                int nl = wn + j*16 + q15;
                float bv = bias[n0 + nl];
                f32x4 v = acc[i][j];
                uint2 u;
                u.x = pkbf((v.x + bv)*mk4.x, (v.y + bv)*mk4.y);
                u.y = pkbf((v.z + bv)*mk4.z, (v.w + bv)*mk4.w);
                *(uint2*)&sm.Ct[nl*132 + ml] = u;
            }
        }
    }
    __syncthreads();

    {
        int row  = tid >> 1;
        int half = (tid & 1) * 64;
        const uint4* src = (const uint4*)&sm.Ct[row*132 + half];
        unsigned short* dst;
        if (z < 2) {
            unsigned short* outp = (z == 0) ? qw : kw;
            int mg = m0 + row;  int b2 = mg >> 11, s = mg & 2047;
            int n  = n0 + half; int hh = n >> 6;
            dst = outp + (((size_t)b2*NH + hh)*S_LEN + s)*DHEAD;
        } else {
            int n  = n0 + row;  int hh = n >> 6, dv = n & 63;
            int b2 = m0 >> 11, s0 = m0 & 2047;
            dst = vt + (((size_t)b2*NH + hh)*DHEAD + dv)*S_LEN + s0 + half;
        }
        #pragma unroll
        for (int c = 0; c < 8; ++c) ((uint4*)dst)[c] = src[c];
    }
}

// ---------------------------------------------------------------------------
// Attention: block = 128 queries x (h, b); 4 waves x 32 queries.
// K staged into LDS with rows PERMUTED by lambda(key) so the QK C-layout,
// exp'd and packed, IS the PV A-fragment in registers (no P LDS round-trip).
//   lambda(key) = (key>>5)*32 + ((key>>2)&1)*16 + ((key>>3)&3)*4 + (key&3)
// K-frag reads stay at rows ks*16+q15 (conflict-free); tile ks reg r of lane
// (quad,q15) = key quad*8 + r + 4*(ks&1) + 32*(ks>>1).
// Q pre-scaled by QSCALE -> scores already in log2 domain -> v_exp_f32.
// V pre-multiplied by mask; denominator = P @ mask via MFMA.
// ---------------------------------------------------------------------------
__global__ __launch_bounds__(256, 2) void attn_mfma(
    const unsigned short* __restrict__ qw, const unsigned short* __restrict__ kw,
    const unsigned short* __restrict__ vt, const unsigned short* __restrict__ mbf,
    float* __restrict__ out)
{
    __shared__ __align__(16) unsigned short Ks[2][64][72];   // [perm key][d]
    __shared__ __align__(16) unsigned short Vs[2][64][72];   // [dv][key]
    __shared__ __align__(16) unsigned short Ms[2][72];       // mask bf16

    const int tid  = threadIdx.x;
    const int lane = tid & 63;
    const int wv   = tid >> 6;
    const int q15  = lane & 15;
    const int quad = lane >> 4;
    const int q0   = blockIdx.x * 128;
    const int h    = blockIdx.y;
    const int b    = blockIdx.z;

    const size_t headoff = ((size_t)b * NH + h) * S_LEN * DHEAD;
    const unsigned short* qb = qw + headoff;
    const unsigned short* kb = kw + headoff;
    const unsigned short* vb = vt + headoff;          // [dv][s]
    const unsigned short* mb = mbf + (size_t)b * S_LEN;

    // Q fragments (B-operand): B[k=d at quad*8+j][n=query at lane&15]
    bf16x8 qf[2][2];
    #pragma unroll
    for (int qi = 0; qi < 2; ++qi) {
        const unsigned short* qr = qb + (size_t)(q0 + wv*32 + qi*16 + q15)*DHEAD;
        qf[qi][0] = *(const bf16x8*)(qr + quad*8);
        qf[qi][1] = *(const bf16x8*)(qr + 32 + quad*8);
    }

    const int srow = tid >> 3;          // 0..31 (key row for staging)
    const int scol = (tid & 7) * 8;     // 0..56
    // permuted LDS row for K (srow in [0,32); +32 row adds +32 to lambda)
    const int prow = ((srow >> 2) & 1) * 16 + ((srow >> 3) & 3) * 4 + (srow & 3);

    f32x4 zero4 = {0.f, 0.f, 0.f, 0.f};
    f32x4 oacc[2][4];
    f32x4 dacc[2];
    #pragma unroll
    for (int qi = 0; qi < 2; ++qi) {
        dacc[qi] = zero4;
        #pragma unroll
        for (int nj = 0; nj < 4; ++nj) oacc[qi][nj] = zero4;
    }

    // prologue: prefetch tile 0 into registers
    uint4 kr0, kr1, vr0, vr1, mr = {0,0,0,0};
    kr0 = *(const uint4*)(kb + (size_t)(srow)     *DHEAD + scol);
    kr1 = *(const uint4*)(kb + (size_t)(srow + 32)*DHEAD + scol);
    vr0 = *(const uint4*)(vb + (size_t)(srow)     *S_LEN + scol);
    vr1 = *(const uint4*)(vb + (size_t)(srow + 32)*S_LEN + scol);
    if (tid < 8) mr = *(const uint4*)(mb + tid*8);

    for (int t = 0; t < 32; ++t) {
        const int buf = t & 1;
        const int k0  = t * 64;
        // commit staged regs to LDS[buf]
        *(uint4*)&Ks[buf][prow][scol]      = kr0;
        *(uint4*)&Ks[buf][prow + 32][scol] = kr1;
        *(uint4*)&Vs[buf][srow][scol]      = vr0;
        *(uint4*)&Vs[buf][srow + 32][scol] = vr1;
        if (tid < 8) *(uint4*)&Ms[buf][tid*8] = mr;
        // issue prefetch for tile t+1 (clamped; overlaps compute below)
        const int kn = (t < 31) ? k0 + 64 : 0;
        kr0 = *(const uint4*)(kb + (size_t)(kn + srow)     *DHEAD + scol);
        kr1 = *(const uint4*)(kb + (size_t)(kn + srow + 32)*DHEAD + scol);
        vr0 = *(const uint4*)(vb + (size_t)(srow)     *S_LEN + kn + scol);
        vr1 = *(const uint4*)(vb + (size_t)(srow + 32)*S_LEN + kn + scol);
        if (tid < 8) mr = *(const uint4*)(mb + kn + tid*8);
        __syncthreads();

        // ---- QK^T: 4 tiles; tile ks reg r = key quad*8+r+4*(ks&1)+32*(ks>>1)
        f32x4 s[2][4];
        #pragma unroll
        for (int ks = 0; ks < 4; ++ks) {
            bf16x8 kf0 = *(const bf16x8*)&Ks[buf][ks*16 + q15][quad*8];
            bf16x8 kf1 = *(const bf16x8*)&Ks[buf][ks*16 + q15][32 + quad*8];
            #pragma unroll
            for (int qi = 0; qi < 2; ++qi) {
                f32x4 a = MFMA16(kf0, qf[qi][0], zero4);
                s[qi][ks] = MFMA16(kf1, qf[qi][1], a);
            }
        }
        // ---- exp2 + pack: registers ARE the PV A-fragments ----
        bf16x8 pf[2][2];
        #pragma unroll
        for (int qi = 0; qi < 2; ++qi) {
            uint4 u0, u1;
            u0.x = pkbf(EXP2F(s[qi][0][0]), EXP2F(s[qi][0][1]));
            u0.y = pkbf(EXP2F(s[qi][0][2]), EXP2F(s[qi][0][3]));
            u0.z = pkbf(EXP2F(s[qi][1][0]), EXP2F(s[qi][1][1]));
            u0.w = pkbf(EXP2F(s[qi][1][2]), EXP2F(s[qi][1][3]));
            u1.x = pkbf(EXP2F(s[qi][2][0]), EXP2F(s[qi][2][1]));
            u1.y = pkbf(EXP2F(s[qi][2][2]), EXP2F(s[qi][2][3]));
            u1.z = pkbf(EXP2F(s[qi][3][0]), EXP2F(s[qi][3][1]));
            u1.w = pkbf(EXP2F(s[qi][3][2]), EXP2F(s[qi][3][3]));
            union { uint4 u; bf16x8 h; } c0, c1;
            c0.u = u0; c1.u = u1;
            pf[qi][0] = c0.h;   // keys quad*8+0..7   (k-pos 0..31 of frag0)
            pf[qi][1] = c1.h;   // keys 32+quad*8+0..7
        }
        // ---- denominator: P @ mask ----
        bf16x8 mf0 = *(const bf16x8*)&Ms[buf][quad*8];
        bf16x8 mf1 = *(const bf16x8*)&Ms[buf][32 + quad*8];
        #pragma unroll
        for (int qi = 0; qi < 2; ++qi) {
            dacc[qi] = MFMA16(pf[qi][0], mf0, dacc[qi]);
            dacc[qi] = MFMA16(pf[qi][1], mf1, dacc[qi]);
        }
        // ---- PV: V' rows (already mask-scaled) from LDS ----
        #pragma unroll
        for (int nj = 0; nj < 4; ++nj) {
            bf16x8 vf0 = *(const bf16x8*)&Vs[buf][nj*16 + q15][quad*8];
            bf16x8 vf1 = *(const bf16x8*)&Vs[buf][nj*16 + q15][32 + quad*8];
            #pragma unroll
            for (int qi = 0; qi < 2; ++qi) {
                oacc[qi][nj] = MFMA16(pf[qi][0], vf0, oacc[qi][nj]);
                oacc[qi][nj] = MFMA16(pf[qi][1], vf1, oacc[qi][nj]);
            }
        }
    }

    // epilogue: D rows quad*4+r = query; denom replicated across n lanes
    #pragma unroll
    for (int qi = 0; qi < 2; ++qi)
        #pragma unroll
        for (int r = 0; r < 4; ++r) {
            float inv = 1.0f / (dacc[qi][r] + 1e-8f);
            size_t row = ((size_t)b*S_LEN + q0 + wv*32 + qi*16 + quad*4 + r)*DMODEL
                       + h*DHEAD;
            #pragma unroll
            for (int nj = 0; nj < 4; ++nj)
                out[row + nj*16 + q15] = oacc[qi][nj][r] * inv;
        }
}

// ---------------------------------------------------------------------------
extern "C" void kernel_launch(void* const* d_in, const int* in_sizes, int n_in,
                              void* d_out, int out_size, void* d_ws, size_t ws_size,
                              hipStream_t stream) {
    const float* Q    = (const float*)d_in[0];
    const float* msk  = (const float*)d_in[1];
    const float* W_Q  = (const float*)d_in[2];
    const float* b_Q  = (const float*)d_in[3];
    const float* W_K  = (const float*)d_in[4];
    const float* b_K  = (const float*)d_in[5];
    const float* W_V  = (const float*)d_in[6];
    const float* b_V  = (const float*)d_in[7];
    float* out = (float*)d_out;

    unsigned short* wsu = (unsigned short*)d_ws;
    unsigned short* Qbf = wsu;                                   // 4M elems
    unsigned short* Wbf = Qbf + (size_t)4096*1024;               // 3M
    unsigned short* qwb = Wbf + (size_t)3*1024*1024;             // 4M
    unsigned short* kwb = qwb + (size_t)4*1024*1024;             // 4M
    unsigned short* vtb = kwb + (size_t)4*1024*1024;             // 4M
    unsigned short* mbf = vtb + (size_t)4*1024*1024;             // 4K

    cvt_all<<<3586, 256, 0, stream>>>(Q, W_Q, W_K, W_V, msk, Qbf, Wbf, mbf);

    proj_mfma<<<dim3(8, 32, 3), 256, 0, stream>>>(
        Qbf, Wbf, b_Q, b_K, b_V, msk, qwb, kwb, vtb);

    attn_mfma<<<dim3(S_LEN/128, NH, BATCH), 256, 0, stream>>>(
        qwb, kwb, vtb, mbf, out);
}